// Round 1
// baseline (4769.155 us; speedup 1.0000x reference)
//
#include <hip/hip_runtime.h>
#include <math.h>

// Problem constants (from reference): H1=15, H2=60, H3=20, T=15, IN=1
#define HH   15          // LSTM hidden size (both layers)
#define G4   60          // 4*HH gate rows
#define TT   15          // time steps
#define NH2  60          // head layer 1 width
#define NH3  20          // head layer 2 width

__device__ __forceinline__ float fast_rcp(float x) {
    return __builtin_amdgcn_rcpf(x);   // v_rcp_f32, ~1 ulp
}
__device__ __forceinline__ float sigm(float x) {
    // 1/(1+exp(-x)); exp(-x)->inf => rcp(inf)=0 => 0 (correct), no NaN
    return fast_rcp(1.0f + __expf(-x));
}
__device__ __forceinline__ float tanhx(float x) {
    // tanh(x) = 1 - 2/(1+exp(2x)); exp->inf => rcp->0 => 1; exp->0 => -1. NaN-safe.
    float e = __expf(2.0f * x);
    return 1.0f - 2.0f * fast_rcp(1.0f + e);
}

// One thread per batch element. Weights staged in LDS (wave-uniform broadcast
// reads). Head collapsed to out[b] = sum_t h2_t[14] * v[t] + c.
__global__ __launch_bounds__(256, 2)
void lstm_fused(const float* __restrict__ x,
                const float* __restrict__ Wih0, const float* __restrict__ Whh0,
                const float* __restrict__ bih0, const float* __restrict__ bhh0,
                const float* __restrict__ Wih1, const float* __restrict__ Whh1,
                const float* __restrict__ bih1, const float* __restrict__ bhh1,
                const float* __restrict__ W1, const float* __restrict__ b1,
                const float* __restrict__ W2, const float* __restrict__ b2,
                const float* __restrict__ W3, const float* __restrict__ b3,
                float* __restrict__ out, int B)
{
    __shared__ float sWih0[G4];        // (60,1)
    __shared__ float sWhh0[G4 * HH];   // (60,15)
    __shared__ float sB0[G4];          // bih0+bhh0
    __shared__ float sWih1[G4 * HH];   // (60,15)
    __shared__ float sWhh1[G4 * HH];   // (60,15)
    __shared__ float sB1[G4];          // bih1+bhh1
    __shared__ float sV[TT];           // collapsed head vector
    __shared__ float sU[NH2];          // temp: W3 @ W2
    __shared__ float sCb;              // collapsed head bias

    const int tid = threadIdx.x;

    // ---- stage weights into LDS (coalesced) ----
    for (int i = tid; i < G4; i += 256) {
        sWih0[i] = Wih0[i];
        sB0[i]   = bih0[i] + bhh0[i];
        sB1[i]   = bih1[i] + bhh1[i];
    }
    for (int i = tid; i < G4 * HH; i += 256) {
        sWhh0[i] = Whh0[i];
        sWih1[i] = Wih1[i];
        sWhh1[i] = Whh1[i];
    }
    // ---- collapse the affine head: u = W3@W2 (60), v = u@W1 (15), c scalar ----
    if (tid < NH2) {
        float u = 0.0f;
        #pragma unroll
        for (int k = 0; k < NH3; ++k) u = fmaf(W3[k], W2[k * NH2 + tid], u);
        sU[tid] = u;
    }
    __syncthreads();
    if (tid < TT) {
        float v = 0.0f;
        for (int j = 0; j < NH2; ++j) v = fmaf(sU[j], W1[j * HH + tid], v);
        sV[tid] = v;
    }
    if (tid == 0) {
        float c = b3[0];
        for (int k = 0; k < NH3; ++k) c = fmaf(W3[k], b2[k], c);
        for (int j = 0; j < NH2; ++j) c = fmaf(sU[j], b1[j], c);
        sCb = c;
    }
    __syncthreads();

    const int b = blockIdx.x * 256 + tid;
    if (b >= B) return;

    const float* xp = x + (size_t)b * TT;

    // per-element LSTM state, all in registers (indices always compile-time)
    float h1[HH], c1[HH], h2[HH], c2[HH];
    #pragma unroll
    for (int u = 0; u < HH; ++u) { h1[u] = 0.0f; c1[u] = 0.0f; h2[u] = 0.0f; c2[u] = 0.0f; }

    float acc = sCb;

    for (int t = 0; t < TT; ++t) {
        const float xt = xp[t];

        // ---------- layer 1 ----------
        float h1n[HH];
        #pragma unroll
        for (int u = 0; u < HH; ++u) {
            float ig = fmaf(sWih0[u],          xt, sB0[u]);
            float fg = fmaf(sWih0[HH + u],     xt, sB0[HH + u]);
            float gg = fmaf(sWih0[2 * HH + u], xt, sB0[2 * HH + u]);
            float og = fmaf(sWih0[3 * HH + u], xt, sB0[3 * HH + u]);
            #pragma unroll
            for (int k = 0; k < HH; ++k) {
                const float hk = h1[k];
                ig = fmaf(sWhh0[(u)          * HH + k], hk, ig);
                fg = fmaf(sWhh0[(HH + u)     * HH + k], hk, fg);
                gg = fmaf(sWhh0[(2 * HH + u) * HH + k], hk, gg);
                og = fmaf(sWhh0[(3 * HH + u) * HH + k], hk, og);
            }
            const float cc = sigm(fg) * c1[u] + sigm(ig) * tanhx(gg);
            c1[u] = cc;
            h1n[u] = sigm(og) * tanhx(cc);
        }

        // ---------- layer 2 (input = h1n) ----------
        float h2n[HH];
        #pragma unroll
        for (int u = 0; u < HH; ++u) {
            float ig = sB1[u];
            float fg = sB1[HH + u];
            float gg = sB1[2 * HH + u];
            float og = sB1[3 * HH + u];
            #pragma unroll
            for (int k = 0; k < HH; ++k) {
                const float hk = h1n[k];
                ig = fmaf(sWih1[(u)          * HH + k], hk, ig);
                fg = fmaf(sWih1[(HH + u)     * HH + k], hk, fg);
                gg = fmaf(sWih1[(2 * HH + u) * HH + k], hk, gg);
                og = fmaf(sWih1[(3 * HH + u) * HH + k], hk, og);
            }
            #pragma unroll
            for (int k = 0; k < HH; ++k) {
                const float hk = h2[k];
                ig = fmaf(sWhh1[(u)          * HH + k], hk, ig);
                fg = fmaf(sWhh1[(HH + u)     * HH + k], hk, fg);
                gg = fmaf(sWhh1[(2 * HH + u) * HH + k], hk, gg);
                og = fmaf(sWhh1[(3 * HH + u) * HH + k], hk, og);
            }
            const float cc = sigm(fg) * c2[u] + sigm(ig) * tanhx(gg);
            c2[u] = cc;
            h2n[u] = sigm(og) * tanhx(cc);
        }

        #pragma unroll
        for (int k = 0; k < HH; ++k) { h1[k] = h1n[k]; h2[k] = h2n[k]; }

        // feat[b,t] = h2_t[14]; accumulate collapsed head online
        acc = fmaf(h2n[HH - 1], sV[t], acc);
    }

    out[b] = acc;
}

extern "C" void kernel_launch(void* const* d_in, const int* in_sizes, int n_in,
                              void* d_out, int out_size, void* d_ws, size_t ws_size,
                              hipStream_t stream) {
    (void)n_in; (void)d_ws; (void)ws_size; (void)out_size;
    const float* x    = (const float*)d_in[0];
    const float* Wih0 = (const float*)d_in[1];
    const float* Whh0 = (const float*)d_in[2];
    const float* bih0 = (const float*)d_in[3];
    const float* bhh0 = (const float*)d_in[4];
    const float* Wih1 = (const float*)d_in[5];
    const float* Whh1 = (const float*)d_in[6];
    const float* bih1 = (const float*)d_in[7];
    const float* bhh1 = (const float*)d_in[8];
    const float* W1   = (const float*)d_in[9];
    const float* b1   = (const float*)d_in[10];
    const float* W2   = (const float*)d_in[11];
    const float* b2   = (const float*)d_in[12];
    const float* W3   = (const float*)d_in[13];
    const float* b3   = (const float*)d_in[14];
    float* out = (float*)d_out;

    const int B = in_sizes[0] / TT;   // 131072
    const int block = 256;
    const int grid = (B + block - 1) / block;

    lstm_fused<<<grid, block, 0, stream>>>(x, Wih0, Whh0, bih0, bhh0,
                                           Wih1, Whh1, bih1, bhh1,
                                           W1, b1, W2, b2, W3, b3, out, B);
}